// Round 6
// baseline (312.690 us; speedup 1.0000x reference)
//
#include <hip/hip_runtime.h>

// B=32, S=577, D=768, H=12, Dh=64. fp32 in/out, bf16 MFMA compute.
#define NB 32
#define SEQ 577
#define SP 640      // padded seq (5*128, 10*64)
#define DM 768
#define NH 12
#define DH 64
#define NC 10       // key chunks of 64

typedef __attribute__((ext_vector_type(8))) short bf16x8;   // K=32 MFMA A/B frag
typedef __attribute__((ext_vector_type(4))) short bf16x4;   // K=16 MFMA A/B frag
typedef __attribute__((ext_vector_type(4))) float f32x4;
typedef __attribute__((ext_vector_type(2))) unsigned int u32x2;
typedef __attribute__((ext_vector_type(4))) unsigned int u32x4;
typedef unsigned short u16;

__device__ __forceinline__ u16 f2bf(float f) {  // RNE float->bf16
  unsigned int u = __builtin_bit_cast(unsigned int, f);
  u += 0x7fffu + ((u >> 16) & 1u);
  return (u16)(u >> 16);
}

// pack two fp32 -> bf16 pair (round-half-up) in one v_perm
__device__ __forceinline__ unsigned int pack_bf2(float a, float b) {
  unsigned int ua = __builtin_bit_cast(unsigned int, a) + 0x8000u;
  unsigned int ub = __builtin_bit_cast(unsigned int, b) + 0x8000u;
  return __builtin_amdgcn_perm(ub, ua, 0x07060302u);  // lo16=bf(a), hi16=bf(b)
}

__device__ __forceinline__ void g2l16(const void* g, void* lds) {
  __builtin_amdgcn_global_load_lds(
      (const __attribute__((address_space(1))) void*)g,
      (__attribute__((address_space(3))) void*)lds, 16, 0, 0);
}

// ---- kernel 1: fp32 -> bf16 cast of hidden_states -------------------------
__global__ void cvt_x_kernel(const float* __restrict__ X, u16* __restrict__ Xb, int n4) {
  int i = blockIdx.x * 256 + threadIdx.x;
  if (i >= n4) return;
  f32x4 v = *reinterpret_cast<const f32x4*>(X + (size_t)i * 4);
  u32x2 p;
  p[0] = (unsigned)f2bf(v[0]) | ((unsigned)f2bf(v[1]) << 16);
  p[1] = (unsigned)f2bf(v[2]) | ((unsigned)f2bf(v[3]) << 16);
  *reinterpret_cast<u32x2*>(Xb + (size_t)i * 4) = p;
}

// ---- kernel 2: cast + transpose weights via LDS tile ----------------------
__global__ __launch_bounds__(256)
void cvt_w_kernel(const float* __restrict__ Wq, const float* __restrict__ Wk,
                  const float* __restrict__ Wv, u16* __restrict__ Wt) {
  __shared__ u16 ld[64 * 72];
  const int m = blockIdx.z;
  const float* W = (m == 0) ? Wq : (m == 1) ? Wk : Wv;
  const int k0 = blockIdx.y * 64, n0 = blockIdx.x * 64;
  const int tid = threadIdx.x;
  const int kr = tid >> 4, c4 = tid & 15;
#pragma unroll
  for (int p = 0; p < 4; ++p) {
    const int k = p * 16 + kr;
    f32x4 v = *reinterpret_cast<const f32x4*>(&W[(size_t)(k0 + k) * DM + n0 + c4 * 4]);
#pragma unroll
    for (int e = 0; e < 4; ++e) ld[(c4 * 4 + e) * 72 + k] = f2bf(v[e]);
  }
  __syncthreads();
  u16* dst = Wt + (size_t)m * DM * DM;
#pragma unroll
  for (int p = 0; p < 2; ++p) {
    const int s = p * 256 + tid;
    const int n = s >> 3, ch = (s & 7) * 8;
    u32x4 w = *reinterpret_cast<const u32x4*>(&ld[n * 72 + ch]);
    *reinterpret_cast<u32x4*>(&dst[(size_t)(n0 + n) * DM + k0 + ch]) = w;
  }
}

// ---- kernel 3: fused QKV GEMM (bf16 MFMA, 256x256 tile, BK=32) ------------
// v7: = v5 counted-vmcnt deep pipeline (4 LDS bufs, depth-3 prefetch,
// vmcnt(8) steady state, 2 sub-phases of 16 MFMA per K-tile) + v6 LDS
// epilogue, RECOMBINED into one 720-block dispatch (the 3-way split left
// CUs idle: 240 blocks @ 1 block/CU < 256 CUs, no tail amortization).
__global__ __launch_bounds__(512, 2)
void qkv_gemm_kernel(const u16* __restrict__ Xb, const u16* __restrict__ Wt,
                     const float* __restrict__ bq, const float* __restrict__ bk,
                     const float* __restrict__ bv,
                     u16* __restrict__ Qw, u16* __restrict__ Kw, u16* __restrict__ Vw) {
  __shared__ alignas(16) u16 sh[256 * 264];  // 132KB; pipeline uses first 128KB

  const int tid = threadIdx.x;
  const int lane = tid & 63;
  const int wid = tid >> 6;          // 0..7
  const int wm = wid >> 2, wn = wid & 3;
  const int l15 = lane & 15, lq = lane >> 4;

  // XCD swizzle: 720 blocks = 8 XCDs x 90; 9 consumers (3 nt x 3 qkv) of
  // each 384KB A-slab adjacent on one XCD (Wt 3.5MB ~ L2-resident).
  const int flat = (blockIdx.z * 3 + blockIdx.y) * 80 + blockIdx.x;
  const int xcd = flat & 7;
  const int j8 = flat >> 3;          // 0..89
  const int xi = j8 / 9;             // 0..9
  const int yz = j8 - xi * 9;        // 0..8
  const int mt = xi * 8 + xcd;       // 0..79
  const int nt = yz % 3;
  const int qkv = yz / 3;

  const u16* Wm = Wt + (size_t)qkv * DM * DM;
  const float* bias = (qkv == 0) ? bq : (qkv == 1) ? bk : bv;

  // staging source pointers: wave stages A entries wid*2, wid*2+1; B same
  const u16* gA[2];
  const u16* gB[2];
#pragma unroll
  for (int s = 0; s < 2; ++s) {
    const int e = wid * 2 + s;       // 0..15
    int r = mt * 256 + e * 16 + l15;
    int br = r / SP;
    int tr = r - br * SP;
    if (tr >= SEQ) tr = SEQ - 1;     // clamp padded rows (finite garbage)
    gA[s] = Xb + (size_t)(br * SEQ + tr) * DM + lq * 8;
    gB[s] = Wm + (size_t)(nt * 256 + e * 16 + l15) * DM + lq * 8;
  }

  f32x4 acc[8][4];
#pragma unroll
  for (int i = 0; i < 8; ++i)
#pragma unroll
    for (int j = 0; j < 4; ++j)
#pragma unroll
      for (int r = 0; r < 4; ++r) acc[i][j][r] = 0.0f;

  auto stageA = [&](int buf, int kt) {
    g2l16(gA[0] + kt * 32, &sh[buf * 8192 + (wid * 2 + 0) * 512]);
    g2l16(gA[1] + kt * 32, &sh[buf * 8192 + (wid * 2 + 1) * 512]);
  };
  auto stageB = [&](int buf, int kt) {
    g2l16(gB[0] + kt * 32, &sh[32768 + buf * 8192 + (wid * 2 + 0) * 512]);
    g2l16(gB[1] + kt * 32, &sh[32768 + buf * 8192 + (wid * 2 + 1) * 512]);
  };

  // prologue: K-tiles 0..2 staged (12 loads/wave); guarantee buf0 only
  stageA(0, 0); stageB(0, 0);
  stageA(1, 1); stageB(1, 1);
  stageA(2, 2); stageB(2, 2);
  asm volatile("s_waitcnt vmcnt(8)" ::: "memory");  // buf0 landed; 1,2 in flight
  __builtin_amdgcn_s_barrier();

  const int NKT = DM / 32;  // 24
  for (int kt = 0; kt < NKT; ++kt) {
    const int buf = kt & 3;
    const int nbuf = (kt + 3) & 3;
    const bool more = (kt + 3 < NKT);  // kt <= 20
    bf16x8 a03[4], bf4[4], a47[4];

    // ---- s0: read A0-3 + B0-3 (buf guaranteed by prev s1); stage next A ----
#pragma unroll
    for (int i = 0; i < 4; ++i)
      a03[i] = *reinterpret_cast<const bf16x8*>(&sh[buf * 8192 + ((wm * 8 + i) * 64 + lane) * 8]);
#pragma unroll
    for (int j = 0; j < 4; ++j)
      bf4[j] = *reinterpret_cast<const bf16x8*>(&sh[32768 + buf * 8192 + ((wn * 4 + j) * 64 + lane) * 8]);
    if (more) stageA(nbuf, kt + 3);
    __builtin_amdgcn_s_barrier();
    __builtin_amdgcn_s_setprio(1);
#pragma unroll
    for (int i = 0; i < 4; ++i)
#pragma unroll
      for (int j = 0; j < 4; ++j)
        acc[i][j] = __builtin_amdgcn_mfma_f32_16x16x32_bf16(a03[i], bf4[j], acc[i][j], 0, 0, 0);
    __builtin_amdgcn_s_setprio(0);
    __builtin_amdgcn_s_barrier();

    // ---- s1: read A4-7; stage next B; counted wait for buf[kt+1] ----
#pragma unroll
    for (int i = 0; i < 4; ++i)
      a47[i] = *reinterpret_cast<const bf16x8*>(&sh[buf * 8192 + ((wm * 8 + 4 + i) * 64 + lane) * 8]);
    if (more) stageB(nbuf, kt + 3);
    if (kt <= NKT - 4) {
      asm volatile("s_waitcnt vmcnt(8)" ::: "memory");   // buf[kt+1] landed, 8 in flight
    } else if (kt == NKT - 3) {
      asm volatile("s_waitcnt vmcnt(4)" ::: "memory");   // tail decay
    } else if (kt == NKT - 2) {
      asm volatile("s_waitcnt vmcnt(0)" ::: "memory");
    }
    __builtin_amdgcn_s_barrier();
    __builtin_amdgcn_s_setprio(1);
#pragma unroll
    for (int i = 0; i < 4; ++i)
#pragma unroll
      for (int j = 0; j < 4; ++j)
        acc[4 + i][j] = __builtin_amdgcn_mfma_f32_16x16x32_bf16(a47[i], bf4[j], acc[4 + i][j], 0, 0, 0);
    __builtin_amdgcn_s_setprio(0);
    __builtin_amdgcn_s_barrier();
  }

  // ---- epilogue phase 1: acc -> LDS tile (bias/scale/pack applied) ----
  const float sfold = 0.18033688011112042f;  // (1/sqrt(64)) * log2(e)
#pragma unroll
  for (int j = 0; j < 4; ++j) {
    const int col = wn * 64 + j * 16 + l15;          // local col 0..255
    const float bb = bias[nt * 256 + col];
#pragma unroll
    for (int i = 0; i < 8; ++i) {
      const int row = wm * 128 + i * 16 + lq * 4;    // local row 0..252
      if (qkv == 2) {
        // V: [col][row] so tr becomes the contiguous axis on re-read
        unsigned p0 = (unsigned)f2bf(acc[i][j][0] + bb) | ((unsigned)f2bf(acc[i][j][1] + bb) << 16);
        unsigned p1 = (unsigned)f2bf(acc[i][j][2] + bb) | ((unsigned)f2bf(acc[i][j][3] + bb) << 16);
        *reinterpret_cast<u32x2*>(&sh[col * 264 + row]) = u32x2{p0, p1};
      } else {
#pragma unroll
        for (int r = 0; r < 4; ++r) {
          float v = acc[i][j][r] + bb;
          if (qkv == 0) v *= sfold;
          sh[(row + r) * 264 + col] = f2bf(v);
        }
      }
    }
  }
  __builtin_amdgcn_s_barrier();

  // ---- epilogue phase 2: LDS -> global, coalesced 16B stores ----
#pragma unroll
  for (int p = 0; p < 16; ++p) {
    const int slot = p * 512 + tid;      // 0..8191
    const int rr = slot >> 5;            // 0..255
    const int cc = (slot & 31) * 8;      // 0..248
    u32x4 w = *reinterpret_cast<const u32x4*>(&sh[rr * 264 + cc]);
    if (qkv == 2) {
      // rr = local d-col, cc..cc+7 = local rows (8 | 640 -> same batch)
      const int gcol = nt * 256 + rr;
      const int h = gcol >> 6, d = gcol & 63;
      const int rg = mt * 256 + cc;
      const int br = rg / SP, tr = rg - br * SP;
      *reinterpret_cast<u32x4*>(&Vw[((size_t)(br * NH + h) * DH + d) * SP + tr]) = w;
    } else {
      const int rg = mt * 256 + rr;
      const int br = rg / SP, tr = rg - br * SP;
      const int gcol = nt * 256 + cc;
      const int h = gcol >> 6, d = gcol & 63;   // cc%64: 8 cols within one head
      u16* dst = ((qkv == 0) ? Qw : Kw) + ((size_t)(br * NH + h) * SP + tr) * DH + d;
      *reinterpret_cast<u32x4*>(dst) = w;
    }
  }
}

// ---- kernel 4: flash attention v4 -----------------------------------------
// v7 changes (attn is VALU-bound: VALUBusy 50%, MfmaUtil 24%):
//  - T13 defer-max (THR=8): wave-uniform __all skip of O-rescale + alpha
//    path when per-chunk max growth <= 8 (log2 units; P <= 2^8, bf16-safe).
//  - T17 left-nested fmax chains -> v_max3_f32 fusion.
#if __has_builtin(__builtin_amdgcn_mfma_f32_16x16x16bf16_1k)
#define MFMA16(a, b, c) __builtin_amdgcn_mfma_f32_16x16x16bf16_1k(a, b, c, 0, 0, 0)
#define HAVE_MFMA16 1
#elif __has_builtin(__builtin_amdgcn_mfma_f32_16x16x16_bf16)
#define MFMA16(a, b, c) __builtin_amdgcn_mfma_f32_16x16x16_bf16(a, b, c, 0, 0, 0)
#define HAVE_MFMA16 1
#else
#define HAVE_MFMA16 0
#endif

__global__ __launch_bounds__(256)
void attn_kernel(const u16* __restrict__ Qw, const u16* __restrict__ Kw,
                 const u16* __restrict__ Vw, float* __restrict__ out) {
  __shared__ alignas(16) u16 Kc[2][8 * 64 * 8];
  __shared__ alignas(16) u16 Vc[2][16 * 64 * 4];

  const int tid = threadIdx.x;
  const int lane = tid & 63;
  const int wid = tid >> 6;
  const int l15 = lane & 15, lq = lane >> 4;

  // XCD-aware decode: grid (5, 384) -> flat 0..1919; each XCD gets a
  // contiguous range of 240 works = 48 complete (b,h) K/V groups.
  const int flat = blockIdx.y * 5 + blockIdx.x;
  const int w = (flat & 7) * 240 + (flat >> 3);
  const int qx = w % 5;
  const int bh = w / 5;
  const int b = bh / NH;
  const int h = bh - b * NH;
  const int q0 = qx * 128 + wid * 32;  // wave: queries q0..q0+31

  const u16* Qb = Qw + (size_t)bh * SP * DH;
  const u16* Kb = Kw + (size_t)bh * SP * DH;
  const u16* Vb = Vw + (size_t)bh * DH * SP;

  // Q B-frags: [qt][half], B[n=q=l15][k=half*32+lq*8+j]
  bf16x8 qf[2][2];
#pragma unroll
  for (int qt = 0; qt < 2; ++qt)
#pragma unroll
    for (int hf = 0; hf < 2; ++hf)
      qf[qt][hf] = *reinterpret_cast<const bf16x8*>(
          &Qb[(q0 + qt * 16 + l15) * DH + hf * 32 + lq * 8]);

  // staging source addresses (chunk-invariant parts)
  const u16* gK = Kb + (size_t)(wid * 16 + l15) * DH + lq * 8;
  const u16* gV = Vb + (size_t)(wid * 16 + l15) * SP + lq * 4;

  float mrow[2] = {-__builtin_inff(), -__builtin_inff()};
  float lrow[2] = {0.0f, 0.0f};
  f32x4 acc[2][4];  // [qt][dt]; d = dt*16+lq*4+r, q = q0+qt*16+l15
#pragma unroll
  for (int qt = 0; qt < 2; ++qt)
#pragma unroll
    for (int dt = 0; dt < 4; ++dt)
#pragma unroll
      for (int r = 0; r < 4; ++r) acc[qt][dt][r] = 0.0f;

  // ---- prologue: stage chunk 0 into buffer 0 ----
  g2l16(gK, &Kc[0][(wid * 2 + 0) * 512]);
  g2l16(gK + 32, &Kc[0][(wid * 2 + 1) * 512]);
  {
    u32x2 v[4];
#pragma unroll
    for (int t = 0; t < 4; ++t)
      v[t] = *reinterpret_cast<const u32x2*>(gV + t * 16);
#pragma unroll
    for (int t = 0; t < 4; ++t)
      *reinterpret_cast<u32x2*>(&Vc[0][((wid * 4 + t) * 64 + lane) * 4]) = v[t];
  }
  __syncthreads();

  for (int c = 0; c < NC; ++c) {
    const int cur = c & 1;
    const int c0 = c * 64;
    // ---- prefetch chunk c+1 (async; drained by end-of-loop barrier) ----
    u32x2 vn[4];
    if (c + 1 < NC) {
      const u16* gKn = gK + (size_t)(c0 + 64) * DH;
      g2l16(gKn, &Kc[cur ^ 1][(wid * 2 + 0) * 512]);
      g2l16(gKn + 32, &Kc[cur ^ 1][(wid * 2 + 1) * 512]);
#pragma unroll
      for (int t = 0; t < 4; ++t)
        vn[t] = *reinterpret_cast<const u32x2*>(gV + (c0 + 64) + t * 16);
    }

    // ---- S^T = K·Q^T from LDS K ----
    f32x4 s[2][4];
    __builtin_amdgcn_s_setprio(1);
#pragma unroll
    for (int t = 0; t < 4; ++t) {
      bf16x8 kf0 = *reinterpret_cast<const bf16x8*>(&Kc[cur][((t * 2 + 0) * 64 + lane) * 8]);
      bf16x8 kf1 = *reinterpret_cast<const bf16x8*>(&Kc[cur][((t * 2 + 1) * 64 + lane) * 8]);
#pragma unroll
      for (int qt = 0; qt < 2; ++qt) {
        f32x4 z;
#pragma unroll
        for (int r = 0; r < 4; ++r) z[r] = 0.0f;
        z = __builtin_amdgcn_mfma_f32_16x16x32_bf16(kf0, qf[qt][0], z, 0, 0, 0);
        z = __builtin_amdgcn_mfma_f32_16x16x32_bf16(kf1, qf[qt][1], z, 0, 0, 0);
        s[qt][t] = z;
      }
    }
    __builtin_amdgcn_s_setprio(0);
    // ---- mask padded keys (uniform branch, last chunk only) ----
    if (c0 + 64 > SEQ) {
#pragma unroll
      for (int qt = 0; qt < 2; ++qt)
#pragma unroll
        for (int t = 0; t < 4; ++t)
#pragma unroll
          for (int r = 0; r < 4; ++r) {
            int key = c0 + t * 16 + lq * 4 + r;
            s[qt][t][r] = (key < SEQ) ? s[qt][t][r] : -__builtin_inff();
          }
    }
    // ---- online softmax (in-lane over 16 + shfl 16,32; defer-max T13) ----
    float alpha[2];
    bool skipq[2];
    unsigned int pku[2][4][2];
#pragma unroll
    for (int qt = 0; qt < 2; ++qt) {
      // left-nested chains -> v_max3 fusion
      float t0 = fmaxf(fmaxf(fmaxf(s[qt][0][0], s[qt][0][1]), s[qt][0][2]), s[qt][0][3]);
      float t1 = fmaxf(fmaxf(fmaxf(s[qt][1][0], s[qt][1][1]), s[qt][1][2]), s[qt][1][3]);
      float t2 = fmaxf(fmaxf(fmaxf(s[qt][2][0], s[qt][2][1]), s[qt][2][2]), s[qt][2][3]);
      float t3 = fmaxf(fmaxf(fmaxf(s[qt][3][0], s[qt][3][1]), s[qt][3][2]), s[qt][3][3]);
      float mx = fmaxf(fmaxf(fmaxf(t0, t1), t2), t3);
      mx = fmaxf(mx, __shfl_xor(mx, 16));
      mx = fmaxf(mx, __shfl_xor(mx, 32));
      // defer-max: keep old running max when growth <= 8 (wave-uniform)
      const bool sk = __all(mx - mrow[qt] <= 8.0f) != 0;
      skipq[qt] = sk;
      float mn = sk ? mrow[qt] : fmaxf(mrow[qt], mx);
      alpha[qt] = sk ? 1.0f : __builtin_amdgcn_exp2f(mrow[qt] - mn);
      mrow[qt] = mn;
      float sm = 0.0f;
#pragma unroll
      for (int t = 0; t < 4; ++t) {
        float p0 = __builtin_amdgcn_exp2f(s[qt][t][0] - mn);
        float p1 = __builtin_amdgcn_exp2f(s[qt][t][1] - mn);
        float p2 = __builtin_amdgcn_exp2f(s[qt][t][2] - mn);
        float p3 = __builtin_amdgcn_exp2f(s[qt][t][3] - mn);
        sm += (p0 + p1) + (p2 + p3);
        pku[qt][t][0] = pack_bf2(p0, p1);
        pku[qt][t][1] = pack_bf2(p2, p3);
      }
      sm += __shfl_xor(sm, 16);
      sm += __shfl_xor(sm, 32);
      lrow[qt] = sk ? (lrow[qt] + sm) : (lrow[qt] * alpha[qt] + sm);
    }

#if HAVE_MFMA16
    // ---- PV: O^T = Vt·P^T (K=16 MFMA; vf shared across q-tiles) ----
    __builtin_amdgcn_s_setprio(1);
#pragma unroll
    for (int dt = 0; dt < 4; ++dt) {
      bf16x4 vf[4];
#pragma unroll
      for (int t = 0; t < 4; ++t)
        vf[t] = *reinterpret_cast<const bf16x4*>(&Vc[cur][((dt * 4 + t) * 64 + lane) * 4]);
#pragma unroll
      for (int qt = 0; qt < 2; ++qt) {
        f32x4 a = acc[qt][dt];
        if (!skipq[qt]) {  // wave-uniform: rescale skipped when max kept
#pragma unroll
          for (int r = 0; r < 4; ++r) a[r] *= alpha[qt];
        }
#pragma unroll
        for (int t = 0; t < 4; ++t) {
          bf16x4 pf = __builtin_bit_cast(bf16x4, u32x2{pku[qt][t][0], pku[qt][t][1]});
          a = MFMA16(vf[t], pf, a);
        }
        acc[qt][dt] = a;
      }
    }
    __builtin_amdgcn_s_setprio(0);
#else
    // ---- fallback: K=32 MFMA, B-frag via bpermute (v2-verified pattern) ----
#pragma unroll
    for (int qt = 0; qt < 2; ++qt) {
      unsigned int bfrag[2][4];
#pragma unroll
      for (int hh = 0; hh < 2; ++hh)
#pragma unroll
        for (int w2 = 0; w2 < 4; ++w2) {
          int srcl = l15 + 16 * (2 * (lq & 1) + (w2 >> 1));
          unsigned int lo = (unsigned int)__shfl((int)pku[qt][2 * hh][w2 & 1], srcl);
          unsigned int hi = (unsigned int)__shfl((int)pku[qt][2 * hh + 1][w2 & 1], srcl);
          bfrag[hh][w2] = (lq < 2) ? lo : hi;
        }
#pragma unroll
      for (int dt = 0; dt < 4; ++dt) {
        f32x4 a = acc[qt][dt];
        if (!skipq[qt]) {
#pragma unroll
          for (int r = 0; r < 4; ++r) a[r] *= alpha[qt];
        }
#pragma unroll
        for (int hh = 0; hh < 2; ++hh) {
          u32x2 w0 = *reinterpret_cast<const u32x2*>(&Vc[cur][((dt * 4 + 2 * hh) * 64 + lane) * 4]);
          u32x2 w1 = *reinterpret_cast<const u32x2*>(&Vc[cur][((dt * 4 + 2 * hh + 1) * 64 + lane) * 4]);
          u32x4 vw = {w0[0], w0[1], w1[0], w1[1]};
          u32x4 pw = {bfrag[hh][0], bfrag[hh][1], bfrag[hh][2], bfrag[hh][3]};
          a = __builtin_amdgcn_mfma_f32_16x16x32_bf16(
              __builtin_bit_cast(bf16x8, vw), __builtin_bit_cast(bf16x8, pw), a, 0, 0, 0);
        }
        acc[qt][dt] = a;
      }
    }
#endif

    // ---- write prefetched V into the other buffer, then barrier ----
    if (c + 1 < NC) {
#pragma unroll
      for (int t = 0; t < 4; ++t)
        *reinterpret_cast<u32x2*>(&Vc[cur ^ 1][((wid * 4 + t) * 64 + lane) * 4]) = vn[t];
    }
    __syncthreads();
  }

  // ---- epilogue: direct stores (lane holds 4 consecutive d -> 16B store) ----
#pragma unroll
  for (int qt = 0; qt < 2; ++qt) {
    int q = q0 + qt * 16 + l15;
    if (q < SEQ) {
      float rl = 1.0f / lrow[qt];
      float* orow = out + ((size_t)b * SEQ + q) * DM + h * DH;
#pragma unroll
      for (int dt = 0; dt < 4; ++dt) {
        f32x4 v = acc[qt][dt];
#pragma unroll
        for (int r = 0; r < 4; ++r) v[r] *= rl;
        *reinterpret_cast<f32x4*>(&orow[dt * 16 + lq * 4]) = v;
      }
    }
  }
}

extern "C" void kernel_launch(void* const* d_in, const int* in_sizes, int n_in,
                              void* d_out, int out_size, void* d_ws, size_t ws_size,
                              hipStream_t stream) {
  (void)in_sizes; (void)n_in; (void)out_size; (void)ws_size;
  const float* X  = (const float*)d_in[0];
  const float* Wq = (const float*)d_in[1];
  const float* bq = (const float*)d_in[2];
  const float* Wk = (const float*)d_in[3];
  const float* bk = (const float*)d_in[4];
  const float* Wv = (const float*)d_in[5];
  const float* bv = (const float*)d_in[6];
  float* out = (float*)d_out;

  char* ws = (char*)d_ws;
  u16* Xb = (u16*)ws;
  u16* Wt = (u16*)(ws + 28366848);
  u16* Qw = (u16*)(ws + 28366848 + 3538944);
  u16* Kw = Qw + (size_t)NB * NH * SP * DH;
  u16* Vw = Kw + (size_t)NB * NH * SP * DH;

  cvt_x_kernel<<<dim3(13848), 256, 0, stream>>>(X, Xb, 3545088);
  cvt_w_kernel<<<dim3(12, 12, 3), 256, 0, stream>>>(Wq, Wk, Wv, Wt);
  qkv_gemm_kernel<<<dim3(80, 3, 3), 512, 0, stream>>>(Xb, Wt, bq, bk, bv, Qw, Kw, Vw);
  attn_kernel<<<dim3(5, NB * NH), 256, 0, stream>>>(Qw, Kw, Vw, out);
}

// Round 7
// 302.619 us; speedup vs baseline: 1.0333x; 1.0333x over previous
//
#include <hip/hip_runtime.h>

// B=32, S=577, D=768, H=12, Dh=64. fp32 in/out, bf16 MFMA compute.
#define NB 32
#define SEQ 577
#define SP 640      // padded seq (5*128, 10*64)
#define DM 768
#define NH 12
#define DH 64
#define NC 10       // key chunks of 64

typedef __attribute__((ext_vector_type(8))) short bf16x8;   // K=32 MFMA A/B frag
typedef __attribute__((ext_vector_type(4))) short bf16x4;   // K=16 MFMA A/B frag
typedef __attribute__((ext_vector_type(4))) float f32x4;
typedef __attribute__((ext_vector_type(2))) unsigned int u32x2;
typedef __attribute__((ext_vector_type(4))) unsigned int u32x4;
typedef unsigned short u16;

__device__ __forceinline__ u16 f2bf(float f) {  // RNE float->bf16
  unsigned int u = __builtin_bit_cast(unsigned int, f);
  u += 0x7fffu + ((u >> 16) & 1u);
  return (u16)(u >> 16);
}

// pack two fp32 -> bf16 pair (round-half-up) in one v_perm
__device__ __forceinline__ unsigned int pack_bf2(float a, float b) {
  unsigned int ua = __builtin_bit_cast(unsigned int, a) + 0x8000u;
  unsigned int ub = __builtin_bit_cast(unsigned int, b) + 0x8000u;
  return __builtin_amdgcn_perm(ub, ua, 0x07060302u);  // lo16=bf(a), hi16=bf(b)
}

__device__ __forceinline__ void g2l16(const void* g, void* lds) {
  __builtin_amdgcn_global_load_lds(
      (const __attribute__((address_space(1))) void*)g,
      (__attribute__((address_space(3))) void*)lds, 16, 0, 0);
}

// ---- kernel 1: fp32 -> bf16 cast of hidden_states -------------------------
__global__ void cvt_x_kernel(const float* __restrict__ X, u16* __restrict__ Xb, int n4) {
  int i = blockIdx.x * 256 + threadIdx.x;
  if (i >= n4) return;
  f32x4 v = *reinterpret_cast<const f32x4*>(X + (size_t)i * 4);
  u32x2 p;
  p[0] = (unsigned)f2bf(v[0]) | ((unsigned)f2bf(v[1]) << 16);
  p[1] = (unsigned)f2bf(v[2]) | ((unsigned)f2bf(v[3]) << 16);
  *reinterpret_cast<u32x2*>(Xb + (size_t)i * 4) = p;
}

// ---- kernel 2: cast + transpose weights via LDS tile ----------------------
__global__ __launch_bounds__(256)
void cvt_w_kernel(const float* __restrict__ Wq, const float* __restrict__ Wk,
                  const float* __restrict__ Wv, u16* __restrict__ Wt) {
  __shared__ u16 ld[64 * 72];
  const int m = blockIdx.z;
  const float* W = (m == 0) ? Wq : (m == 1) ? Wk : Wv;
  const int k0 = blockIdx.y * 64, n0 = blockIdx.x * 64;
  const int tid = threadIdx.x;
  const int kr = tid >> 4, c4 = tid & 15;
#pragma unroll
  for (int p = 0; p < 4; ++p) {
    const int k = p * 16 + kr;
    f32x4 v = *reinterpret_cast<const f32x4*>(&W[(size_t)(k0 + k) * DM + n0 + c4 * 4]);
#pragma unroll
    for (int e = 0; e < 4; ++e) ld[(c4 * 4 + e) * 72 + k] = f2bf(v[e]);
  }
  __syncthreads();
  u16* dst = Wt + (size_t)m * DM * DM;
#pragma unroll
  for (int p = 0; p < 2; ++p) {
    const int s = p * 256 + tid;
    const int n = s >> 3, ch = (s & 7) * 8;
    u32x4 w = *reinterpret_cast<const u32x4*>(&ld[n * 72 + ch]);
    *reinterpret_cast<u32x4*>(&dst[(size_t)(n0 + n) * DM + k0 + ch]) = w;
  }
}

// ---- kernel 3: fused QKV GEMM (bf16 MFMA, 256x256 tile, BK=32) ------------
// v8: merged-phase counted-vmcnt pipeline. Per K-tile ONE phase:
//   { 12x ds_read(buf kt) | stage A+B(kt+3) | vmcnt(8) | barrier |
//     setprio + 32 MFMA | barrier }
// Halves barrier count vs v7 (2 per K-tile), single 32-MFMA cluster, 12
// reads for the compiler to interleave lgkmcnt against. Hazards: buf[kt+1]
// guaranteed by iter-kt vmcnt(8)+barrier (its 4 loads are oldest of 12 in
// flight); WAR on slot (kt+3)&3: its readers finished MFMA before the
// preceding closing barrier, stage issue follows it. Tail decay 8->4->0.
__global__ __launch_bounds__(512, 2)
void qkv_gemm_kernel(const u16* __restrict__ Xb, const u16* __restrict__ Wt,
                     const float* __restrict__ bq, const float* __restrict__ bk,
                     const float* __restrict__ bv,
                     u16* __restrict__ Qw, u16* __restrict__ Kw, u16* __restrict__ Vw) {
  __shared__ alignas(16) u16 sh[256 * 264];  // 132KB; pipeline uses first 128KB

  const int tid = threadIdx.x;
  const int lane = tid & 63;
  const int wid = tid >> 6;          // 0..7
  const int wm = wid >> 2, wn = wid & 3;
  const int l15 = lane & 15, lq = lane >> 4;

  // XCD swizzle: 720 blocks = 8 XCDs x 90; 9 consumers (3 nt x 3 qkv) of
  // each 384KB A-slab adjacent on one XCD (Wt 3.5MB ~ L2-resident).
  const int flat = (blockIdx.z * 3 + blockIdx.y) * 80 + blockIdx.x;
  const int xcd = flat & 7;
  const int j8 = flat >> 3;          // 0..89
  const int xi = j8 / 9;             // 0..9
  const int yz = j8 - xi * 9;        // 0..8
  const int mt = xi * 8 + xcd;       // 0..79
  const int nt = yz % 3;
  const int qkv = yz / 3;

  const u16* Wm = Wt + (size_t)qkv * DM * DM;
  const float* bias = (qkv == 0) ? bq : (qkv == 1) ? bk : bv;

  // staging source pointers: wave stages A entries wid*2, wid*2+1; B same
  const u16* gA[2];
  const u16* gB[2];
#pragma unroll
  for (int s = 0; s < 2; ++s) {
    const int e = wid * 2 + s;       // 0..15
    int r = mt * 256 + e * 16 + l15;
    int br = r / SP;
    int tr = r - br * SP;
    if (tr >= SEQ) tr = SEQ - 1;     // clamp padded rows (finite garbage)
    gA[s] = Xb + (size_t)(br * SEQ + tr) * DM + lq * 8;
    gB[s] = Wm + (size_t)(nt * 256 + e * 16 + l15) * DM + lq * 8;
  }

  f32x4 acc[8][4];
#pragma unroll
  for (int i = 0; i < 8; ++i)
#pragma unroll
    for (int j = 0; j < 4; ++j)
#pragma unroll
      for (int r = 0; r < 4; ++r) acc[i][j][r] = 0.0f;

  auto stageA = [&](int buf, int kt) {
    g2l16(gA[0] + kt * 32, &sh[buf * 8192 + (wid * 2 + 0) * 512]);
    g2l16(gA[1] + kt * 32, &sh[buf * 8192 + (wid * 2 + 1) * 512]);
  };
  auto stageB = [&](int buf, int kt) {
    g2l16(gB[0] + kt * 32, &sh[32768 + buf * 8192 + (wid * 2 + 0) * 512]);
    g2l16(gB[1] + kt * 32, &sh[32768 + buf * 8192 + (wid * 2 + 1) * 512]);
  };

  // prologue: K-tiles 0..2 staged (12 loads/wave); guarantee buf0 only
  stageA(0, 0); stageB(0, 0);
  stageA(1, 1); stageB(1, 1);
  stageA(2, 2); stageB(2, 2);
  asm volatile("s_waitcnt vmcnt(8)" ::: "memory");  // buf0 landed; 1,2 in flight
  __builtin_amdgcn_s_barrier();

  const int NKT = DM / 32;  // 24
  for (int kt = 0; kt < NKT; ++kt) {
    const int buf = kt & 3;
    const int nbuf = (kt + 3) & 3;
    const bool more = (kt + 3 < NKT);  // kt <= 20
    bf16x8 af[8], bf4[4];

    // ---- ds_read all 12 frags of buf[kt] ----
#pragma unroll
    for (int i = 0; i < 8; ++i)
      af[i] = *reinterpret_cast<const bf16x8*>(&sh[buf * 8192 + ((wm * 8 + i) * 64 + lane) * 8]);
#pragma unroll
    for (int j = 0; j < 4; ++j)
      bf4[j] = *reinterpret_cast<const bf16x8*>(&sh[32768 + buf * 8192 + ((wn * 4 + j) * 64 + lane) * 8]);

    // ---- stage K-tile kt+3 (4 loads) ----
    if (more) { stageA(nbuf, kt + 3); stageB(nbuf, kt + 3); }

    // ---- counted wait: buf[kt+1] landed, rest in flight ----
    if (kt <= NKT - 4) {
      asm volatile("s_waitcnt vmcnt(8)" ::: "memory");
    } else if (kt == NKT - 3) {
      asm volatile("s_waitcnt vmcnt(4)" ::: "memory");
    } else if (kt == NKT - 2) {
      asm volatile("s_waitcnt vmcnt(0)" ::: "memory");
    }
    __builtin_amdgcn_s_barrier();

    // ---- 32-MFMA cluster ----
    __builtin_amdgcn_s_setprio(1);
#pragma unroll
    for (int i = 0; i < 8; ++i)
#pragma unroll
      for (int j = 0; j < 4; ++j)
        acc[i][j] = __builtin_amdgcn_mfma_f32_16x16x32_bf16(af[i], bf4[j], acc[i][j], 0, 0, 0);
    __builtin_amdgcn_s_setprio(0);
    __builtin_amdgcn_s_barrier();
  }

  // ---- epilogue phase 1: acc -> LDS tile (bias/scale/pack applied) ----
  const float sfold = 0.18033688011112042f;  // (1/sqrt(64)) * log2(e)
#pragma unroll
  for (int j = 0; j < 4; ++j) {
    const int col = wn * 64 + j * 16 + l15;          // local col 0..255
    const float bb = bias[nt * 256 + col];
#pragma unroll
    for (int i = 0; i < 8; ++i) {
      const int row = wm * 128 + i * 16 + lq * 4;    // local row 0..252
      if (qkv == 2) {
        // V: [col][row] so tr becomes the contiguous axis on re-read
        unsigned p0 = (unsigned)f2bf(acc[i][j][0] + bb) | ((unsigned)f2bf(acc[i][j][1] + bb) << 16);
        unsigned p1 = (unsigned)f2bf(acc[i][j][2] + bb) | ((unsigned)f2bf(acc[i][j][3] + bb) << 16);
        *reinterpret_cast<u32x2*>(&sh[col * 264 + row]) = u32x2{p0, p1};
      } else {
#pragma unroll
        for (int r = 0; r < 4; ++r) {
          float v = acc[i][j][r] + bb;
          if (qkv == 0) v *= sfold;
          sh[(row + r) * 264 + col] = f2bf(v);
        }
      }
    }
  }
  __builtin_amdgcn_s_barrier();

  // ---- epilogue phase 2: LDS -> global, coalesced 16B stores ----
#pragma unroll
  for (int p = 0; p < 16; ++p) {
    const int slot = p * 512 + tid;      // 0..8191
    const int rr = slot >> 5;            // 0..255
    const int cc = (slot & 31) * 8;      // 0..248
    u32x4 w = *reinterpret_cast<const u32x4*>(&sh[rr * 264 + cc]);
    if (qkv == 2) {
      // rr = local d-col, cc..cc+7 = local rows (8 | 640 -> same batch)
      const int gcol = nt * 256 + rr;
      const int h = gcol >> 6, d = gcol & 63;
      const int rg = mt * 256 + cc;
      const int br = rg / SP, tr = rg - br * SP;
      *reinterpret_cast<u32x4*>(&Vw[((size_t)(br * NH + h) * DH + d) * SP + tr]) = w;
    } else {
      const int rg = mt * 256 + rr;
      const int br = rg / SP, tr = rg - br * SP;
      const int gcol = nt * 256 + cc;
      const int h = gcol >> 6, d = gcol & 63;   // cc%64: 8 cols within one head
      u16* dst = ((qkv == 0) ? Qw : Kw) + ((size_t)(br * NH + h) * SP + tr) * DH + d;
      *reinterpret_cast<u32x4*>(dst) = w;
    }
  }
}

// ---- kernel 4: flash attention v3 (round-5 version, measured 99us) --------
// Block = 4 waves = 128 queries (wave owns 32 = 2 q-tiles of 16).
// S^T = K·Q^T keeps softmax in-lane; P stays in-lane as K=16 PV B-frag.
// XCD swizzle + setprio around MFMA clusters. NO defer-max (regressed r6:
// VGPR 84->88 crossed the 512/6 granule, occ 26->19.6%, attn 99->117us).
#if __has_builtin(__builtin_amdgcn_mfma_f32_16x16x16bf16_1k)
#define MFMA16(a, b, c) __builtin_amdgcn_mfma_f32_16x16x16bf16_1k(a, b, c, 0, 0, 0)
#define HAVE_MFMA16 1
#elif __has_builtin(__builtin_amdgcn_mfma_f32_16x16x16_bf16)
#define MFMA16(a, b, c) __builtin_amdgcn_mfma_f32_16x16x16_bf16(a, b, c, 0, 0, 0)
#define HAVE_MFMA16 1
#else
#define HAVE_MFMA16 0
#endif

__global__ __launch_bounds__(256)
void attn_kernel(const u16* __restrict__ Qw, const u16* __restrict__ Kw,
                 const u16* __restrict__ Vw, float* __restrict__ out) {
  __shared__ alignas(16) u16 Kc[2][8 * 64 * 8];
  __shared__ alignas(16) u16 Vc[2][16 * 64 * 4];

  const int tid = threadIdx.x;
  const int lane = tid & 63;
  const int wid = tid >> 6;
  const int l15 = lane & 15, lq = lane >> 4;

  // XCD-aware decode: grid (5, 384) -> flat 0..1919; each XCD gets a
  // contiguous range of 240 works = 48 complete (b,h) K/V groups.
  const int flat = blockIdx.y * 5 + blockIdx.x;
  const int w = (flat & 7) * 240 + (flat >> 3);
  const int qx = w % 5;
  const int bh = w / 5;
  const int b = bh / NH;
  const int h = bh - b * NH;
  const int q0 = qx * 128 + wid * 32;  // wave: queries q0..q0+31

  const u16* Qb = Qw + (size_t)bh * SP * DH;
  const u16* Kb = Kw + (size_t)bh * SP * DH;
  const u16* Vb = Vw + (size_t)bh * DH * SP;

  // Q B-frags: [qt][half], B[n=q=l15][k=half*32+lq*8+j]
  bf16x8 qf[2][2];
#pragma unroll
  for (int qt = 0; qt < 2; ++qt)
#pragma unroll
    for (int hf = 0; hf < 2; ++hf)
      qf[qt][hf] = *reinterpret_cast<const bf16x8*>(
          &Qb[(q0 + qt * 16 + l15) * DH + hf * 32 + lq * 8]);

  // staging source addresses (chunk-invariant parts)
  const u16* gK = Kb + (size_t)(wid * 16 + l15) * DH + lq * 8;
  const u16* gV = Vb + (size_t)(wid * 16 + l15) * SP + lq * 4;

  float mrow[2] = {-__builtin_inff(), -__builtin_inff()};
  float lrow[2] = {0.0f, 0.0f};
  f32x4 acc[2][4];  // [qt][dt]; d = dt*16+lq*4+r, q = q0+qt*16+l15
#pragma unroll
  for (int qt = 0; qt < 2; ++qt)
#pragma unroll
    for (int dt = 0; dt < 4; ++dt)
#pragma unroll
      for (int r = 0; r < 4; ++r) acc[qt][dt][r] = 0.0f;

  // ---- prologue: stage chunk 0 into buffer 0 ----
  g2l16(gK, &Kc[0][(wid * 2 + 0) * 512]);
  g2l16(gK + 32, &Kc[0][(wid * 2 + 1) * 512]);
  {
    u32x2 v[4];
#pragma unroll
    for (int t = 0; t < 4; ++t)
      v[t] = *reinterpret_cast<const u32x2*>(gV + t * 16);
#pragma unroll
    for (int t = 0; t < 4; ++t)
      *reinterpret_cast<u32x2*>(&Vc[0][((wid * 4 + t) * 64 + lane) * 4]) = v[t];
  }
  __syncthreads();

  for (int c = 0; c < NC; ++c) {
    const int cur = c & 1;
    const int c0 = c * 64;
    // ---- prefetch chunk c+1 (async; drained by end-of-loop barrier) ----
    u32x2 vn[4];
    if (c + 1 < NC) {
      const u16* gKn = gK + (size_t)(c0 + 64) * DH;
      g2l16(gKn, &Kc[cur ^ 1][(wid * 2 + 0) * 512]);
      g2l16(gKn + 32, &Kc[cur ^ 1][(wid * 2 + 1) * 512]);
#pragma unroll
      for (int t = 0; t < 4; ++t)
        vn[t] = *reinterpret_cast<const u32x2*>(gV + (c0 + 64) + t * 16);
    }

    // ---- S^T = K·Q^T from LDS K ----
    f32x4 s[2][4];
    __builtin_amdgcn_s_setprio(1);
#pragma unroll
    for (int t = 0; t < 4; ++t) {
      bf16x8 kf0 = *reinterpret_cast<const bf16x8*>(&Kc[cur][((t * 2 + 0) * 64 + lane) * 8]);
      bf16x8 kf1 = *reinterpret_cast<const bf16x8*>(&Kc[cur][((t * 2 + 1) * 64 + lane) * 8]);
#pragma unroll
      for (int qt = 0; qt < 2; ++qt) {
        f32x4 z;
#pragma unroll
        for (int r = 0; r < 4; ++r) z[r] = 0.0f;
        z = __builtin_amdgcn_mfma_f32_16x16x32_bf16(kf0, qf[qt][0], z, 0, 0, 0);
        z = __builtin_amdgcn_mfma_f32_16x16x32_bf16(kf1, qf[qt][1], z, 0, 0, 0);
        s[qt][t] = z;
      }
    }
    __builtin_amdgcn_s_setprio(0);
    // ---- mask padded keys (uniform branch, last chunk only) ----
    if (c0 + 64 > SEQ) {
#pragma unroll
      for (int qt = 0; qt < 2; ++qt)
#pragma unroll
        for (int t = 0; t < 4; ++t)
#pragma unroll
          for (int r = 0; r < 4; ++r) {
            int key = c0 + t * 16 + lq * 4 + r;
            s[qt][t][r] = (key < SEQ) ? s[qt][t][r] : -__builtin_inff();
          }
    }
    // ---- online softmax (in-lane over 16 + shfl 16,32) ----
    float alpha[2];
    unsigned int pku[2][4][2];
#pragma unroll
    for (int qt = 0; qt < 2; ++qt) {
      float mx = s[qt][0][0];
#pragma unroll
      for (int t = 0; t < 4; ++t)
#pragma unroll
        for (int r = 0; r < 4; ++r) mx = fmaxf(mx, s[qt][t][r]);
      mx = fmaxf(mx, __shfl_xor(mx, 16));
      mx = fmaxf(mx, __shfl_xor(mx, 32));
      float mn = fmaxf(mrow[qt], mx);
      alpha[qt] = __builtin_amdgcn_exp2f(mrow[qt] - mn);
      mrow[qt] = mn;
      float sm = 0.0f;
#pragma unroll
      for (int t = 0; t < 4; ++t) {
        float p0 = __builtin_amdgcn_exp2f(s[qt][t][0] - mn);
        float p1 = __builtin_amdgcn_exp2f(s[qt][t][1] - mn);
        float p2 = __builtin_amdgcn_exp2f(s[qt][t][2] - mn);
        float p3 = __builtin_amdgcn_exp2f(s[qt][t][3] - mn);
        sm += (p0 + p1) + (p2 + p3);
        pku[qt][t][0] = pack_bf2(p0, p1);
        pku[qt][t][1] = pack_bf2(p2, p3);
      }
      sm += __shfl_xor(sm, 16);
      sm += __shfl_xor(sm, 32);
      lrow[qt] = lrow[qt] * alpha[qt] + sm;
    }

#if HAVE_MFMA16
    // ---- PV: O^T = Vt·P^T (K=16 MFMA; vf shared across q-tiles) ----
    __builtin_amdgcn_s_setprio(1);
#pragma unroll
    for (int dt = 0; dt < 4; ++dt) {
      bf16x4 vf[4];
#pragma unroll
      for (int t = 0; t < 4; ++t)
        vf[t] = *reinterpret_cast<const bf16x4*>(&Vc[cur][((dt * 4 + t) * 64 + lane) * 4]);
#pragma unroll
      for (int qt = 0; qt < 2; ++qt) {
        f32x4 a = acc[qt][dt];
#pragma unroll
        for (int r = 0; r < 4; ++r) a[r] *= alpha[qt];
#pragma unroll
        for (int t = 0; t < 4; ++t) {
          bf16x4 pf = __builtin_bit_cast(bf16x4, u32x2{pku[qt][t][0], pku[qt][t][1]});
          a = MFMA16(vf[t], pf, a);
        }
        acc[qt][dt] = a;
      }
    }
    __builtin_amdgcn_s_setprio(0);
#else
    // ---- fallback: K=32 MFMA, B-frag via bpermute (v2-verified pattern) ----
#pragma unroll
    for (int qt = 0; qt < 2; ++qt) {
      unsigned int bfrag[2][4];
#pragma unroll
      for (int hh = 0; hh < 2; ++hh)
#pragma unroll
        for (int w2 = 0; w2 < 4; ++w2) {
          int srcl = l15 + 16 * (2 * (lq & 1) + (w2 >> 1));
          unsigned int lo = (unsigned int)__shfl((int)pku[qt][2 * hh][w2 & 1], srcl);
          unsigned int hi = (unsigned int)__shfl((int)pku[qt][2 * hh + 1][w2 & 1], srcl);
          bfrag[hh][w2] = (lq < 2) ? lo : hi;
        }
#pragma unroll
      for (int dt = 0; dt < 4; ++dt) {
        f32x4 a = acc[qt][dt];
#pragma unroll
        for (int r = 0; r < 4; ++r) a[r] *= alpha[qt];
#pragma unroll
        for (int hh = 0; hh < 2; ++hh) {
          u32x2 w0 = *reinterpret_cast<const u32x2*>(&Vc[cur][((dt * 4 + 2 * hh) * 64 + lane) * 4]);
          u32x2 w1 = *reinterpret_cast<const u32x2*>(&Vc[cur][((dt * 4 + 2 * hh + 1) * 64 + lane) * 4]);
          u32x4 vw = {w0[0], w0[1], w1[0], w1[1]};
          u32x4 pw = {bfrag[hh][0], bfrag[hh][1], bfrag[hh][2], bfrag[hh][3]};
          a = __builtin_amdgcn_mfma_f32_16x16x32_bf16(
              __builtin_bit_cast(bf16x8, vw), __builtin_bit_cast(bf16x8, pw), a, 0, 0, 0);
        }
        acc[qt][dt] = a;
      }
    }
#endif

    // ---- write prefetched V into the other buffer, then barrier ----
    if (c + 1 < NC) {
#pragma unroll
      for (int t = 0; t < 4; ++t)
        *reinterpret_cast<u32x2*>(&Vc[cur ^ 1][((wid * 4 + t) * 64 + lane) * 4]) = vn[t];
    }
    __syncthreads();
  }

  // ---- epilogue: direct stores (lane holds 4 consecutive d -> 16B store) ----
#pragma unroll
  for (int qt = 0; qt < 2; ++qt) {
    int q = q0 + qt * 16 + l15;
    if (q < SEQ) {
      float rl = 1.0f / lrow[qt];
      float* orow = out + ((size_t)b * SEQ + q) * DM + h * DH;
#pragma unroll
      for (int dt = 0; dt < 4; ++dt) {
        f32x4 v = acc[qt][dt];
#pragma unroll
        for (int r = 0; r < 4; ++r) v[r] *= rl;
        *reinterpret_cast<f32x4*>(&orow[dt * 16 + lq * 4]) = v;
      }
    }
  }
}

extern "C" void kernel_launch(void* const* d_in, const int* in_sizes, int n_in,
                              void* d_out, int out_size, void* d_ws, size_t ws_size,
                              hipStream_t stream) {
  (void)in_sizes; (void)n_in; (void)out_size; (void)ws_size;
  const float* X  = (const float*)d_in[0];
  const float* Wq = (const float*)d_in[1];
  const float* bq = (const float*)d_in[2];
  const float* Wk = (const float*)d_in[3];
  const float* bk = (const float*)d_in[4];
  const float* Wv = (const float*)d_in[5];
  const float* bv = (const float*)d_in[6];
  float* out = (float*)d_out;

  char* ws = (char*)d_ws;
  u16* Xb = (u16*)ws;
  u16* Wt = (u16*)(ws + 28366848);
  u16* Qw = (u16*)(ws + 28366848 + 3538944);
  u16* Kw = Qw + (size_t)NB * NH * SP * DH;
  u16* Vw = Kw + (size_t)NB * NH * SP * DH;

  cvt_x_kernel<<<dim3(13848), 256, 0, stream>>>(X, Xb, 3545088);
  cvt_w_kernel<<<dim3(12, 12, 3), 256, 0, stream>>>(Wq, Wk, Wv, Wt);
  qkv_gemm_kernel<<<dim3(80, 3, 3), 512, 0, stream>>>(Xb, Wt, bq, bk, bv, Qw, Kw, Vw);
  attn_kernel<<<dim3(5, NB * NH), 256, 0, stream>>>(Qw, Kw, Vw, out);
}

// Round 8
// 298.663 us; speedup vs baseline: 1.0470x; 1.0132x over previous
//
#include <hip/hip_runtime.h>

// B=32, S=577, D=768, H=12, Dh=64. fp32 in/out, bf16 MFMA compute.
#define NB 32
#define SEQ 577
#define SP 640      // padded seq (5*128, 10*64)
#define DM 768
#define NH 12
#define DH 64
#define NC 10       // key chunks of 64
#define CVT_XBLK 2048

typedef __attribute__((ext_vector_type(8))) short bf16x8;   // K=32 MFMA A/B frag
typedef __attribute__((ext_vector_type(4))) short bf16x4;   // K=16 MFMA A/B frag
typedef __attribute__((ext_vector_type(4))) float f32x4;
typedef __attribute__((ext_vector_type(2))) unsigned int u32x2;
typedef __attribute__((ext_vector_type(4))) unsigned int u32x4;
typedef unsigned short u16;

__device__ __forceinline__ u16 f2bf(float f) {  // RNE float->bf16
  unsigned int u = __builtin_bit_cast(unsigned int, f);
  u += 0x7fffu + ((u >> 16) & 1u);
  return (u16)(u >> 16);
}

// pack two fp32 -> bf16 pair (round-half-up) in one v_perm
__device__ __forceinline__ unsigned int pack_bf2(float a, float b) {
  unsigned int ua = __builtin_bit_cast(unsigned int, a) + 0x8000u;
  unsigned int ub = __builtin_bit_cast(unsigned int, b) + 0x8000u;
  return __builtin_amdgcn_perm(ub, ua, 0x07060302u);  // lo16=bf(a), hi16=bf(b)
}

__device__ __forceinline__ void g2l16(const void* g, void* lds) {
  __builtin_amdgcn_global_load_lds(
      (const __attribute__((address_space(1))) void*)g,
      (__attribute__((address_space(3))) void*)lds, 16, 0, 0);
}

// ---- kernel 1: fused casts ------------------------------------------------
// blocks [0, CVT_XBLK): grid-stride fp32->bf16 cast of hidden_states.
// blocks [CVT_XBLK, +432): 64x64 LDS-tiled cast+transpose of Wq/Wk/Wv.
// One dispatch instead of two: fewer launch gaps; grid-stride X loop per G11
// (13848 tiny blocks -> 2048 blocks x ~6.8 iters).
__global__ __launch_bounds__(256)
void cvt_kernel(const float* __restrict__ X, u16* __restrict__ Xb,
                const float* __restrict__ Wq, const float* __restrict__ Wk,
                const float* __restrict__ Wv, u16* __restrict__ Wt) {
  __shared__ u16 ld[64 * 72];
  const int tid = threadIdx.x;
  if (blockIdx.x < CVT_XBLK) {
    const int n4 = 3545088;  // B*S*D/4
    for (int i = blockIdx.x * 256 + tid; i < n4; i += CVT_XBLK * 256) {
      f32x4 v = *reinterpret_cast<const f32x4*>(X + (size_t)i * 4);
      u32x2 p;
      p[0] = pack_bf2(v[0], v[1]);
      p[1] = pack_bf2(v[2], v[3]);
      // pack_bf2 is round-half-up; match previous RNE exactly instead:
      p[0] = (unsigned)f2bf(v[0]) | ((unsigned)f2bf(v[1]) << 16);
      p[1] = (unsigned)f2bf(v[2]) | ((unsigned)f2bf(v[3]) << 16);
      *reinterpret_cast<u32x2*>(Xb + (size_t)i * 4) = p;
    }
  } else {
    const int idx = blockIdx.x - CVT_XBLK;   // 0..431
    const int m = idx / 144;                 // qkv
    const int rem = idx - m * 144;
    const int by = rem / 12, bx = rem - by * 12;
    const int k0 = by * 64, n0 = bx * 64;
    const float* W = (m == 0) ? Wq : (m == 1) ? Wk : Wv;
    const int kr = tid >> 4, c4 = tid & 15;
#pragma unroll
    for (int p = 0; p < 4; ++p) {
      const int k = p * 16 + kr;
      f32x4 v = *reinterpret_cast<const f32x4*>(&W[(size_t)(k0 + k) * DM + n0 + c4 * 4]);
#pragma unroll
      for (int e = 0; e < 4; ++e) ld[(c4 * 4 + e) * 72 + k] = f2bf(v[e]);
    }
    __syncthreads();
    u16* dst = Wt + (size_t)m * DM * DM;
#pragma unroll
    for (int p = 0; p < 2; ++p) {
      const int s = p * 256 + tid;
      const int n = s >> 3, ch = (s & 7) * 8;
      u32x4 w = *reinterpret_cast<const u32x4*>(&ld[n * 72 + ch]);
      *reinterpret_cast<u32x4*>(&dst[(size_t)(n0 + n) * DM + k0 + ch]) = w;
    }
  }
}

// ---- kernel 3: fused QKV GEMM (bf16 MFMA, 256x256 tile, BK=32) ------------
// v9: = v8 merged-phase counted-vmcnt pipeline, kt loop FULLY UNROLLED:
// buf/nbuf/tail-waits compile-time, stage offsets fold into global_load_lds
// immediates, per-iter address VALU gone, scheduler pipelines across tiles.
__global__ __launch_bounds__(512, 2)
void qkv_gemm_kernel(const u16* __restrict__ Xb, const u16* __restrict__ Wt,
                     const float* __restrict__ bq, const float* __restrict__ bk,
                     const float* __restrict__ bv,
                     u16* __restrict__ Qw, u16* __restrict__ Kw, u16* __restrict__ Vw) {
  __shared__ alignas(16) u16 sh[256 * 264];  // 132KB; pipeline uses first 128KB

  const int tid = threadIdx.x;
  const int lane = tid & 63;
  const int wid = tid >> 6;          // 0..7
  const int wm = wid >> 2, wn = wid & 3;
  const int l15 = lane & 15, lq = lane >> 4;

  // XCD swizzle: 720 blocks = 8 XCDs x 90; 9 consumers (3 nt x 3 qkv) of
  // each 384KB A-slab adjacent on one XCD (Wt 3.5MB ~ L2-resident).
  const int flat = (blockIdx.z * 3 + blockIdx.y) * 80 + blockIdx.x;
  const int xcd = flat & 7;
  const int j8 = flat >> 3;          // 0..89
  const int xi = j8 / 9;             // 0..9
  const int yz = j8 - xi * 9;        // 0..8
  const int mt = xi * 8 + xcd;       // 0..79
  const int nt = yz % 3;
  const int qkv = yz / 3;

  const u16* Wm = Wt + (size_t)qkv * DM * DM;
  const float* bias = (qkv == 0) ? bq : (qkv == 1) ? bk : bv;

  // staging source pointers: wave stages A entries wid*2, wid*2+1; B same
  const u16* gA[2];
  const u16* gB[2];
#pragma unroll
  for (int s = 0; s < 2; ++s) {
    const int e = wid * 2 + s;       // 0..15
    int r = mt * 256 + e * 16 + l15;
    int br = r / SP;
    int tr = r - br * SP;
    if (tr >= SEQ) tr = SEQ - 1;     // clamp padded rows (finite garbage)
    gA[s] = Xb + (size_t)(br * SEQ + tr) * DM + lq * 8;
    gB[s] = Wm + (size_t)(nt * 256 + e * 16 + l15) * DM + lq * 8;
  }

  f32x4 acc[8][4];
#pragma unroll
  for (int i = 0; i < 8; ++i)
#pragma unroll
    for (int j = 0; j < 4; ++j)
#pragma unroll
      for (int r = 0; r < 4; ++r) acc[i][j][r] = 0.0f;

  auto stageA = [&](int buf, int kt) {
    g2l16(gA[0] + kt * 32, &sh[buf * 8192 + (wid * 2 + 0) * 512]);
    g2l16(gA[1] + kt * 32, &sh[buf * 8192 + (wid * 2 + 1) * 512]);
  };
  auto stageB = [&](int buf, int kt) {
    g2l16(gB[0] + kt * 32, &sh[32768 + buf * 8192 + (wid * 2 + 0) * 512]);
    g2l16(gB[1] + kt * 32, &sh[32768 + buf * 8192 + (wid * 2 + 1) * 512]);
  };

  // prologue: K-tiles 0..2 staged (12 loads/wave); guarantee buf0 only
  stageA(0, 0); stageB(0, 0);
  stageA(1, 1); stageB(1, 1);
  stageA(2, 2); stageB(2, 2);
  asm volatile("s_waitcnt vmcnt(8)" ::: "memory");  // buf0 landed; 1,2 in flight
  __builtin_amdgcn_s_barrier();

  const int NKT = DM / 32;  // 24
#pragma unroll
  for (int kt = 0; kt < NKT; ++kt) {
    const int buf = kt & 3;
    const int nbuf = (kt + 3) & 3;
    const bool more = (kt + 3 < NKT);  // kt <= 20
    bf16x8 af[8], bf4[4];

    // ---- ds_read all 12 frags of buf[kt] ----
#pragma unroll
    for (int i = 0; i < 8; ++i)
      af[i] = *reinterpret_cast<const bf16x8*>(&sh[buf * 8192 + ((wm * 8 + i) * 64 + lane) * 8]);
#pragma unroll
    for (int j = 0; j < 4; ++j)
      bf4[j] = *reinterpret_cast<const bf16x8*>(&sh[32768 + buf * 8192 + ((wn * 4 + j) * 64 + lane) * 8]);

    // ---- stage K-tile kt+3 (4 loads) ----
    if (more) { stageA(nbuf, kt + 3); stageB(nbuf, kt + 3); }

    // ---- counted wait: buf[kt+1] landed, rest in flight ----
    if (kt <= NKT - 4) {
      asm volatile("s_waitcnt vmcnt(8)" ::: "memory");
    } else if (kt == NKT - 3) {
      asm volatile("s_waitcnt vmcnt(4)" ::: "memory");
    } else if (kt == NKT - 2) {
      asm volatile("s_waitcnt vmcnt(0)" ::: "memory");
    }
    __builtin_amdgcn_s_barrier();

    // ---- 32-MFMA cluster ----
    __builtin_amdgcn_s_setprio(1);
#pragma unroll
    for (int i = 0; i < 8; ++i)
#pragma unroll
      for (int j = 0; j < 4; ++j)
        acc[i][j] = __builtin_amdgcn_mfma_f32_16x16x32_bf16(af[i], bf4[j], acc[i][j], 0, 0, 0);
    __builtin_amdgcn_s_setprio(0);
    __builtin_amdgcn_s_barrier();
  }

  // ---- epilogue phase 1: acc -> LDS tile (bias/scale/pack applied) ----
  const float sfold = 0.18033688011112042f;  // (1/sqrt(64)) * log2(e)
#pragma unroll
  for (int j = 0; j < 4; ++j) {
    const int col = wn * 64 + j * 16 + l15;          // local col 0..255
    const float bb = bias[nt * 256 + col];
#pragma unroll
    for (int i = 0; i < 8; ++i) {
      const int row = wm * 128 + i * 16 + lq * 4;    // local row 0..252
      if (qkv == 2) {
        // V: [col][row] so tr becomes the contiguous axis on re-read
        unsigned p0 = (unsigned)f2bf(acc[i][j][0] + bb) | ((unsigned)f2bf(acc[i][j][1] + bb) << 16);
        unsigned p1 = (unsigned)f2bf(acc[i][j][2] + bb) | ((unsigned)f2bf(acc[i][j][3] + bb) << 16);
        *reinterpret_cast<u32x2*>(&sh[col * 264 + row]) = u32x2{p0, p1};
      } else {
#pragma unroll
        for (int r = 0; r < 4; ++r) {
          float v = acc[i][j][r] + bb;
          if (qkv == 0) v *= sfold;
          sh[(row + r) * 264 + col] = f2bf(v);
        }
      }
    }
  }
  __builtin_amdgcn_s_barrier();

  // ---- epilogue phase 2: LDS -> global, coalesced 16B stores ----
#pragma unroll
  for (int p = 0; p < 16; ++p) {
    const int slot = p * 512 + tid;      // 0..8191
    const int rr = slot >> 5;            // 0..255
    const int cc = (slot & 31) * 8;      // 0..248
    u32x4 w = *reinterpret_cast<const u32x4*>(&sh[rr * 264 + cc]);
    if (qkv == 2) {
      // rr = local d-col, cc..cc+7 = local rows (8 | 640 -> same batch)
      const int gcol = nt * 256 + rr;
      const int h = gcol >> 6, d = gcol & 63;
      const int rg = mt * 256 + cc;
      const int br = rg / SP, tr = rg - br * SP;
      *reinterpret_cast<u32x4*>(&Vw[((size_t)(br * NH + h) * DH + d) * SP + tr]) = w;
    } else {
      const int rg = mt * 256 + rr;
      const int br = rg / SP, tr = rg - br * SP;
      const int gcol = nt * 256 + cc;
      const int h = gcol >> 6, d = gcol & 63;   // cc%64: 8 cols within one head
      u16* dst = ((qkv == 0) ? Qw : Kw) + ((size_t)(br * NH + h) * SP + tr) * DH + d;
      *reinterpret_cast<u32x4*>(dst) = w;
    }
  }
}

// ---- kernel 4: flash attention v3 (round-5 version, measured 99us) --------
// Block = 4 waves = 128 queries (wave owns 32 = 2 q-tiles of 16).
// S^T = K·Q^T keeps softmax in-lane; P stays in-lane as K=16 PV B-frag.
// XCD swizzle + setprio around MFMA clusters. NO defer-max (regressed r6:
// VGPR 84->88 crossed the 512/6 granule, occ 26->19.6%, attn 99->117us).
#if __has_builtin(__builtin_amdgcn_mfma_f32_16x16x16bf16_1k)
#define MFMA16(a, b, c) __builtin_amdgcn_mfma_f32_16x16x16bf16_1k(a, b, c, 0, 0, 0)
#define HAVE_MFMA16 1
#elif __has_builtin(__builtin_amdgcn_mfma_f32_16x16x16_bf16)
#define MFMA16(a, b, c) __builtin_amdgcn_mfma_f32_16x16x16_bf16(a, b, c, 0, 0, 0)
#define HAVE_MFMA16 1
#else
#define HAVE_MFMA16 0
#endif

__global__ __launch_bounds__(256)
void attn_kernel(const u16* __restrict__ Qw, const u16* __restrict__ Kw,
                 const u16* __restrict__ Vw, float* __restrict__ out) {
  __shared__ alignas(16) u16 Kc[2][8 * 64 * 8];
  __shared__ alignas(16) u16 Vc[2][16 * 64 * 4];

  const int tid = threadIdx.x;
  const int lane = tid & 63;
  const int wid = tid >> 6;
  const int l15 = lane & 15, lq = lane >> 4;

  // XCD-aware decode: grid (5, 384) -> flat 0..1919; each XCD gets a
  // contiguous range of 240 works = 48 complete (b,h) K/V groups.
  const int flat = blockIdx.y * 5 + blockIdx.x;
  const int w = (flat & 7) * 240 + (flat >> 3);
  const int qx = w % 5;
  const int bh = w / 5;
  const int b = bh / NH;
  const int h = bh - b * NH;
  const int q0 = qx * 128 + wid * 32;  // wave: queries q0..q0+31

  const u16* Qb = Qw + (size_t)bh * SP * DH;
  const u16* Kb = Kw + (size_t)bh * SP * DH;
  const u16* Vb = Vw + (size_t)bh * DH * SP;

  // Q B-frags: [qt][half], B[n=q=l15][k=half*32+lq*8+j]
  bf16x8 qf[2][2];
#pragma unroll
  for (int qt = 0; qt < 2; ++qt)
#pragma unroll
    for (int hf = 0; hf < 2; ++hf)
      qf[qt][hf] = *reinterpret_cast<const bf16x8*>(
          &Qb[(q0 + qt * 16 + l15) * DH + hf * 32 + lq * 8]);

  // staging source addresses (chunk-invariant parts)
  const u16* gK = Kb + (size_t)(wid * 16 + l15) * DH + lq * 8;
  const u16* gV = Vb + (size_t)(wid * 16 + l15) * SP + lq * 4;

  float mrow[2] = {-__builtin_inff(), -__builtin_inff()};
  float lrow[2] = {0.0f, 0.0f};
  f32x4 acc[2][4];  // [qt][dt]; d = dt*16+lq*4+r, q = q0+qt*16+l15
#pragma unroll
  for (int qt = 0; qt < 2; ++qt)
#pragma unroll
    for (int dt = 0; dt < 4; ++dt)
#pragma unroll
      for (int r = 0; r < 4; ++r) acc[qt][dt][r] = 0.0f;

  // ---- prologue: stage chunk 0 into buffer 0 ----
  g2l16(gK, &Kc[0][(wid * 2 + 0) * 512]);
  g2l16(gK + 32, &Kc[0][(wid * 2 + 1) * 512]);
  {
    u32x2 v[4];
#pragma unroll
    for (int t = 0; t < 4; ++t)
      v[t] = *reinterpret_cast<const u32x2*>(gV + t * 16);
#pragma unroll
    for (int t = 0; t < 4; ++t)
      *reinterpret_cast<u32x2*>(&Vc[0][((wid * 4 + t) * 64 + lane) * 4]) = v[t];
  }
  __syncthreads();

  for (int c = 0; c < NC; ++c) {
    const int cur = c & 1;
    const int c0 = c * 64;
    // ---- prefetch chunk c+1 (async; drained by end-of-loop barrier) ----
    u32x2 vn[4];
    if (c + 1 < NC) {
      const u16* gKn = gK + (size_t)(c0 + 64) * DH;
      g2l16(gKn, &Kc[cur ^ 1][(wid * 2 + 0) * 512]);
      g2l16(gKn + 32, &Kc[cur ^ 1][(wid * 2 + 1) * 512]);
#pragma unroll
      for (int t = 0; t < 4; ++t)
        vn[t] = *reinterpret_cast<const u32x2*>(gV + (c0 + 64) + t * 16);
    }

    // ---- S^T = K·Q^T from LDS K ----
    f32x4 s[2][4];
    __builtin_amdgcn_s_setprio(1);
#pragma unroll
    for (int t = 0; t < 4; ++t) {
      bf16x8 kf0 = *reinterpret_cast<const bf16x8*>(&Kc[cur][((t * 2 + 0) * 64 + lane) * 8]);
      bf16x8 kf1 = *reinterpret_cast<const bf16x8*>(&Kc[cur][((t * 2 + 1) * 64 + lane) * 8]);
#pragma unroll
      for (int qt = 0; qt < 2; ++qt) {
        f32x4 z;
#pragma unroll
        for (int r = 0; r < 4; ++r) z[r] = 0.0f;
        z = __builtin_amdgcn_mfma_f32_16x16x32_bf16(kf0, qf[qt][0], z, 0, 0, 0);
        z = __builtin_amdgcn_mfma_f32_16x16x32_bf16(kf1, qf[qt][1], z, 0, 0, 0);
        s[qt][t] = z;
      }
    }
    __builtin_amdgcn_s_setprio(0);
    // ---- mask padded keys (uniform branch, last chunk only) ----
    if (c0 + 64 > SEQ) {
#pragma unroll
      for (int qt = 0; qt < 2; ++qt)
#pragma unroll
        for (int t = 0; t < 4; ++t)
#pragma unroll
          for (int r = 0; r < 4; ++r) {
            int key = c0 + t * 16 + lq * 4 + r;
            s[qt][t][r] = (key < SEQ) ? s[qt][t][r] : -__builtin_inff();
          }
    }
    // ---- online softmax (in-lane over 16 + shfl 16,32) ----
    float alpha[2];
    unsigned int pku[2][4][2];
#pragma unroll
    for (int qt = 0; qt < 2; ++qt) {
      float mx = s[qt][0][0];
#pragma unroll
      for (int t = 0; t < 4; ++t)
#pragma unroll
        for (int r = 0; r < 4; ++r) mx = fmaxf(mx, s[qt][t][r]);
      mx = fmaxf(mx, __shfl_xor(mx, 16));
      mx = fmaxf(mx, __shfl_xor(mx, 32));
      float mn = fmaxf(mrow[qt], mx);
      alpha[qt] = __builtin_amdgcn_exp2f(mrow[qt] - mn);
      mrow[qt] = mn;
      float sm = 0.0f;
#pragma unroll
      for (int t = 0; t < 4; ++t) {
        float p0 = __builtin_amdgcn_exp2f(s[qt][t][0] - mn);
        float p1 = __builtin_amdgcn_exp2f(s[qt][t][1] - mn);
        float p2 = __builtin_amdgcn_exp2f(s[qt][t][2] - mn);
        float p3 = __builtin_amdgcn_exp2f(s[qt][t][3] - mn);
        sm += (p0 + p1) + (p2 + p3);
        pku[qt][t][0] = pack_bf2(p0, p1);
        pku[qt][t][1] = pack_bf2(p2, p3);
      }
      sm += __shfl_xor(sm, 16);
      sm += __shfl_xor(sm, 32);
      lrow[qt] = lrow[qt] * alpha[qt] + sm;
    }

#if HAVE_MFMA16
    // ---- PV: O^T = Vt·P^T (K=16 MFMA; vf shared across q-tiles) ----
    __builtin_amdgcn_s_setprio(1);
#pragma unroll
    for (int dt = 0; dt < 4; ++dt) {
      bf16x4 vf[4];
#pragma unroll
      for (int t = 0; t < 4; ++t)
        vf[t] = *reinterpret_cast<const bf16x4*>(&Vc[cur][((dt * 4 + t) * 64 + lane) * 4]);
#pragma unroll
      for (int qt = 0; qt < 2; ++qt) {
        f32x4 a = acc[qt][dt];
#pragma unroll
        for (int r = 0; r < 4; ++r) a[r] *= alpha[qt];
#pragma unroll
        for (int t = 0; t < 4; ++t) {
          bf16x4 pf = __builtin_bit_cast(bf16x4, u32x2{pku[qt][t][0], pku[qt][t][1]});
          a = MFMA16(vf[t], pf, a);
        }
        acc[qt][dt] = a;
      }
    }
    __builtin_amdgcn_s_setprio(0);
#else
    // ---- fallback: K=32 MFMA, B-frag via bpermute (v2-verified pattern) ----
#pragma unroll
    for (int qt = 0; qt < 2; ++qt) {
      unsigned int bfrag[2][4];
#pragma unroll
      for (int hh = 0; hh < 2; ++hh)
#pragma unroll
        for (int w2 = 0; w2 < 4; ++w2) {
          int srcl = l15 + 16 * (2 * (lq & 1) + (w2 >> 1));
          unsigned int lo = (unsigned int)__shfl((int)pku[qt][2 * hh][w2 & 1], srcl);
          unsigned int hi = (unsigned int)__shfl((int)pku[qt][2 * hh + 1][w2 & 1], srcl);
          bfrag[hh][w2] = (lq < 2) ? lo : hi;
        }
#pragma unroll
      for (int dt = 0; dt < 4; ++dt) {
        f32x4 a = acc[qt][dt];
#pragma unroll
        for (int r = 0; r < 4; ++r) a[r] *= alpha[qt];
#pragma unroll
        for (int hh = 0; hh < 2; ++hh) {
          u32x2 w0 = *reinterpret_cast<const u32x2*>(&Vc[cur][((dt * 4 + 2 * hh) * 64 + lane) * 4]);
          u32x2 w1 = *reinterpret_cast<const u32x2*>(&Vc[cur][((dt * 4 + 2 * hh + 1) * 64 + lane) * 4]);
          u32x4 vw = {w0[0], w0[1], w1[0], w1[1]};
          u32x4 pw = {bfrag[hh][0], bfrag[hh][1], bfrag[hh][2], bfrag[hh][3]};
          a = __builtin_amdgcn_mfma_f32_16x16x32_bf16(
              __builtin_bit_cast(bf16x8, vw), __builtin_bit_cast(bf16x8, pw), a, 0, 0, 0);
        }
        acc[qt][dt] = a;
      }
    }
#endif

    // ---- write prefetched V into the other buffer, then barrier ----
    if (c + 1 < NC) {
#pragma unroll
      for (int t = 0; t < 4; ++t)
        *reinterpret_cast<u32x2*>(&Vc[cur ^ 1][((wid * 4 + t) * 64 + lane) * 4]) = vn[t];
    }
    __syncthreads();
  }

  // ---- epilogue: direct stores (lane holds 4 consecutive d -> 16B store) ----
#pragma unroll
  for (int qt = 0; qt < 2; ++qt) {
    int q = q0 + qt * 16 + l15;
    if (q < SEQ) {
      float rl = 1.0f / lrow[qt];
      float* orow = out + ((size_t)b * SEQ + q) * DM + h * DH;
#pragma unroll
      for (int dt = 0; dt < 4; ++dt) {
        f32x4 v = acc[qt][dt];
#pragma unroll
        for (int r = 0; r < 4; ++r) v[r] *= rl;
        *reinterpret_cast<f32x4*>(&orow[dt * 16 + lq * 4]) = v;
      }
    }
  }
}

extern "C" void kernel_launch(void* const* d_in, const int* in_sizes, int n_in,
                              void* d_out, int out_size, void* d_ws, size_t ws_size,
                              hipStream_t stream) {
  (void)in_sizes; (void)n_in; (void)out_size; (void)ws_size;
  const float* X  = (const float*)d_in[0];
  const float* Wq = (const float*)d_in[1];
  const float* bq = (const float*)d_in[2];
  const float* Wk = (const float*)d_in[3];
  const float* bk = (const float*)d_in[4];
  const float* Wv = (const float*)d_in[5];
  const float* bv = (const float*)d_in[6];
  float* out = (float*)d_out;

  char* ws = (char*)d_ws;
  u16* Xb = (u16*)ws;
  u16* Wt = (u16*)(ws + 28366848);
  u16* Qw = (u16*)(ws + 28366848 + 3538944);
  u16* Kw = Qw + (size_t)NB * NH * SP * DH;
  u16* Vw = Kw + (size_t)NB * NH * SP * DH;

  cvt_kernel<<<dim3(CVT_XBLK + 432), 256, 0, stream>>>(X, Xb, Wq, Wk, Wv, Wt);
  qkv_gemm_kernel<<<dim3(80, 3, 3), 512, 0, stream>>>(Xb, Wt, bq, bk, bv, Qw, Kw, Vw);
  attn_kernel<<<dim3(5, NB * NH), 256, 0, stream>>>(Qw, Kw, Vw, out);
}